// Round 3
// baseline (2720.403 us; speedup 1.0000x reference)
//
#include <hip/hip_runtime.h>
#include <math.h>

#define NN 50000
#define EE 800000

// ---------------- CSR build ----------------

__global__ __launch_bounds__(256) void k_hist(const int* __restrict__ dst, int* __restrict__ deg) {
    int e = blockIdx.x * 256 + threadIdx.x;
    if (e < EE) atomicAdd(&deg[dst[e]], 1);
}

// single-block exclusive scan of deg[0..NN) -> rowptr; deg becomes pos (= rowptr copy)
__global__ __launch_bounds__(1024) void k_scan(int* __restrict__ deg, int* __restrict__ rowptr) {
    __shared__ int part[1024];
    const int t  = threadIdx.x;
    const int CH = (NN + 1023) / 1024;
    const int b  = t * CH;
    const int e  = min(b + CH, NN);
    int sum = 0;
    for (int i = b; i < e; i++) sum += deg[i];
    part[t] = sum;
    __syncthreads();
    for (int off = 1; off < 1024; off <<= 1) {
        int v = (t >= off) ? part[t - off] : 0;
        __syncthreads();
        part[t] += v;
        __syncthreads();
    }
    int run = (t == 0) ? 0 : part[t - 1];
    for (int i = b; i < e; i++) {
        int d = deg[i];
        rowptr[i] = run;
        deg[i]    = run;   // pos
        run += d;
    }
    if (t == 0) rowptr[NN] = EE;
}

__global__ __launch_bounds__(256) void k_scatter(const int* __restrict__ src, const int* __restrict__ dst,
                                                 int* __restrict__ pos, int* __restrict__ eidx,
                                                 int* __restrict__ esrc) {
    int e = blockIdx.x * 256 + threadIdx.x;
    if (e < EE) {
        int d = dst[e];
        int p = atomicAdd(&pos[d], 1);
        eidx[p] = e;
        esrc[p] = src[e];
    }
}

// ---------------- per-layer kernels ----------------

// K1: per-node fused transform, weights register-resident.
// lane j holds column j of fcW, fcU, Wpot. 4 nodes per iteration,
// K-loop = readlane broadcast + v_fmac, no LDS.
__global__ __launch_bounds__(256, 2) void node_transform(
    const float* __restrict__ hin, const float* __restrict__ pot,
    const float* __restrict__ Wpot, const float* __restrict__ bpot,
    const float* __restrict__ fcW, const float* __restrict__ fcU,
    const float* __restrict__ a, const float* __restrict__ gate,
    float* __restrict__ z, float* __restrict__ zs, float* __restrict__ zd,
    float* __restrict__ base)
{
    const int lane = threadIdx.x & 63;

    float wc[64], uc[64], pc[16];
#pragma unroll
    for (int k = 0; k < 64; k++) {
        wc[k] = fcW[k * 64 + lane];
        uc[k] = fcU[k * 64 + lane];
    }
#pragma unroll
    for (int k = 0; k < 16; k++) pc[k] = Wpot[k * 64 + lane];
    const float bv  = bpot[lane];
    const float gv  = gate[lane];
    const float asv = a[lane];
    const float adv = a[64 + lane];

    const int wave   = blockIdx.x * 4 + (threadIdx.x >> 6);
    const int nwaves = gridDim.x * 4;

    for (int n0 = wave * 4; n0 < NN; n0 += nwaves * 4) {
        float hr[4], pr[4];
#pragma unroll
        for (int c = 0; c < 4; c++) {
            int n = n0 + c;
            bool ok = (n < NN);
            hr[c] = ok ? hin[(size_t)n * 64 + lane] : 0.f;
            pr[c] = (ok && lane < 16) ? pot[(size_t)n * 16 + lane] : 0.f;
        }
        float az[4] = {0.f, 0.f, 0.f, 0.f};
        float au[4] = {0.f, 0.f, 0.f, 0.f};
#pragma unroll
        for (int k = 0; k < 64; k++) {
#pragma unroll
            for (int c = 0; c < 4; c++) {
                float hk = __shfl(hr[c], k);
                az[c] = fmaf(hk, wc[k], az[c]);
                au[c] = fmaf(hk, uc[k], au[c]);
            }
        }
        float vv[4] = {bv, bv, bv, bv};
#pragma unroll
        for (int k = 0; k < 16; k++) {
#pragma unroll
            for (int c = 0; c < 4; c++) {
                vv[c] = fmaf(__shfl(pr[c], k), pc[k], vv[c]);
            }
        }
#pragma unroll
        for (int c = 0; c < 4; c++) {
            int n = n0 + c;
            if (n >= NN) break;
            float zj = az[c];
            float rs = zj * asv;
            float rd = zj * adv;
#pragma unroll
            for (int off = 32; off; off >>= 1) {
                rs += __shfl_xor(rs, off);
                rd += __shfl_xor(rd, off);
            }
            z[(size_t)n * 64 + lane]    = zj;
            base[(size_t)n * 64 + lane] = gv * tanhf(vv[c]) * au[c];
            if (lane == 0) { zs[n] = rs; zd[n] = rd; }
        }
    }
}

// K2: streaming dot for BOTH layers: score_t[e] = et[e,:] . a_t
__device__ __forceinline__ void dot_stream(const float* __restrict__ et,
                                           const float* __restrict__ at,
                                           float* __restrict__ score_t,
                                           int gid, int stride, int lane)
{
    const int p = gid & 15;
    const float4 at4 = *reinterpret_cast<const float4*>(at + p * 4);
    const float4* et4 = reinterpret_cast<const float4*>(et);
    for (int i = gid; i < EE * 16; i += stride) {
        float4 v = et4[i];
        float r = v.x * at4.x + v.y * at4.y + v.z * at4.z + v.w * at4.w;
        r += __shfl_xor(r, 8);
        r += __shfl_xor(r, 4);
        r += __shfl_xor(r, 2);
        r += __shfl_xor(r, 1);
        if ((lane & 15) == 0) score_t[i >> 4] = r;
    }
}

__global__ __launch_bounds__(256) void edge_dot2(
    const float* __restrict__ et0, const float* __restrict__ et1,
    const float* __restrict__ a0, const float* __restrict__ a1,
    float* __restrict__ sc0, float* __restrict__ sc1)
{
    const int gid    = blockIdx.x * 256 + threadIdx.x;
    const int stride = gridDim.x * 256;   // multiple of 16
    const int lane   = threadIdx.x & 63;
    dot_stream(et0, a0 + 128, sc0, gid, stride, lane);
    dot_stream(et1, a1 + 128, sc1, gid, stride, lane);
}

// K3: fused per-node softmax + aggregate + finalize. Wave per node.
__global__ __launch_bounds__(256) void node_sm_agg(
    const int* __restrict__ rowptr, const int* __restrict__ eidx, const int* __restrict__ esrc,
    const float* __restrict__ score_t, const float* __restrict__ zs, const float* __restrict__ zd,
    const float* __restrict__ z, const float* __restrict__ base,
    float* __restrict__ out)
{
    const int lane = threadIdx.x & 63;
    const int n    = blockIdx.x * 4 + (threadIdx.x >> 6);
    if (n >= NN) return;

    const int s0  = rowptr[n], s1 = rowptr[n + 1];
    const int deg = s1 - s0;
    const float zdn = zd[n];

    float acc = 0.f;
    float ds;

    if (deg <= 64) {
        const int j = s0 + lane;
        int   sv = 0;
        float sc = -INFINITY;
        if (j < s1) {
            sv = esrc[j];
            float v = score_t[eidx[j]] + zs[sv] + zdn;
            sc = (v >= 0.f) ? v : 0.01f * v;
        }
        float mx = sc;
#pragma unroll
        for (int off = 32; off; off >>= 1) mx = fmaxf(mx, __shfl_xor(mx, off));
        float ex = (j < s1) ? __expf(sc - mx) : 0.f;
        ds = ex;
#pragma unroll
        for (int off = 32; off; off >>= 1) ds += __shfl_xor(ds, off);
        for (int t = 0; t < deg; t++) {
            int   s = __shfl(sv, t);
            float e = __shfl(ex, t);
            acc = fmaf(e, z[(size_t)s * 64 + lane], acc);
        }
    } else {
        // generic fallback (deg > 64): two passes, recompute scores.
        float mx = -INFINITY;
        for (int j = s0 + lane; j < s1; j += 64) {
            float v = score_t[eidx[j]] + zs[esrc[j]] + zdn;
            v = (v >= 0.f) ? v : 0.01f * v;
            mx = fmaxf(mx, v);
        }
#pragma unroll
        for (int off = 32; off; off >>= 1) mx = fmaxf(mx, __shfl_xor(mx, off));
        ds = 0.f;
        for (int c0 = s0; c0 < s1; c0 += 64) {
            const int j = c0 + lane;
            int   sv = 0;
            float ex = 0.f;
            if (j < s1) {
                sv = esrc[j];
                float v = score_t[eidx[j]] + zs[sv] + zdn;
                v = (v >= 0.f) ? v : 0.01f * v;
                ex = __expf(v - mx);
            }
            ds += ex;
            const int cnt = min(64, s1 - c0);
            for (int t = 0; t < cnt; t++) {
                int   s = __shfl(sv, t);
                float e = __shfl(ex, t);
                acc = fmaf(e, z[(size_t)s * 64 + lane], acc);
            }
        }
#pragma unroll
        for (int off = 32; off; off >>= 1) ds += __shfl_xor(ds, off);
    }

    float r = 1.f / ((ds == 0.f) ? 1.f : ds);
    const size_t o = (size_t)n * 64 + lane;
    out[o] = acc * r + base[o];
}

// ---------------- launch ----------------

extern "C" void kernel_launch(void* const* d_in, const int* in_sizes, int n_in,
                              void* d_out, int out_size, void* d_ws, size_t ws_size,
                              hipStream_t stream)
{
    const float* attr  = (const float*)d_in[0];
    const float* pot0  = (const float*)d_in[1];
    const float* pot1  = (const float*)d_in[2];
    const float* et0   = (const float*)d_in[3];
    const float* et1   = (const float*)d_in[4];
    const float* Wpot  = (const float*)d_in[5];
    const float* bpot  = (const float*)d_in[6];
    const float* fcW0  = (const float*)d_in[7];
    const float* fcU0  = (const float*)d_in[8];
    const float* a0    = (const float*)d_in[9];
    const float* gate0 = (const float*)d_in[10];
    const float* fcW1  = (const float*)d_in[11];
    const float* fcU1  = (const float*)d_in[12];
    const float* a1    = (const float*)d_in[13];
    const float* gate1 = (const float*)d_in[14];
    const int*   src   = (const int*)d_in[15];
    const int*   dst   = (const int*)d_in[16];

    float* out = (float*)d_out;

    // workspace layout
    float* ws      = (float*)d_ws;
    float* z       = ws;                    // NN*64
    float* base    = z + NN * 64;           // NN*64
    float* zs      = base + NN * 64;        // NN
    float* zd      = zs + NN;               // NN
    float* sc0     = zd + NN;               // EE
    float* sc1     = sc0 + EE;              // EE
    int*   rowptr  = (int*)(sc1 + EE);      // NN+1
    int*   deg     = rowptr + NN + 1;       // NN (becomes pos)
    int*   eidx    = deg + NN;              // EE
    int*   esrc    = eidx + EE;             // EE

    const int eblk = (EE + 255) / 256;
    const int nblk = (NN + 3) / 4;

    // CSR build (shared by both layers)
    hipMemsetAsync(deg, 0, NN * sizeof(int), stream);
    k_hist<<<eblk, 256, 0, stream>>>(dst, deg);
    k_scan<<<1, 1024, 0, stream>>>(deg, rowptr);
    k_scatter<<<eblk, 256, 0, stream>>>(src, dst, deg, eidx, esrc);

    // streaming edge dots for both layers (independent of everything above)
    edge_dot2<<<2048, 256, 0, stream>>>(et0, et1, a0, a1, sc0, sc1);

    // ---------------- layer 0 ----------------
    node_transform<<<512, 256, 0, stream>>>(attr, pot0, Wpot, bpot, fcW0, fcU0,
                                            a0, gate0, z, zs, zd, base);
    node_sm_agg<<<nblk, 256, 0, stream>>>(rowptr, eidx, esrc, sc0, zs, zd, z, base, out);

    // ---------------- layer 1 ---------------- (h = out from layer 0)
    node_transform<<<512, 256, 0, stream>>>(out, pot1, Wpot, bpot, fcW1, fcU1,
                                            a1, gate1, z, zs, zd, base);
    node_sm_agg<<<nblk, 256, 0, stream>>>(rowptr, eidx, esrc, sc1, zs, zd, z, base, out);
}

// Round 4
// 545.732 us; speedup vs baseline: 4.9849x; 4.9849x over previous
//
#include <hip/hip_runtime.h>
#include <math.h>

#define NN 50000
#define EE 800000

// ---------------- CSR build ----------------

__global__ __launch_bounds__(256) void k_hist(const int* __restrict__ dst, int* __restrict__ deg) {
    int e = blockIdx.x * 256 + threadIdx.x;
    if (e < EE) atomicAdd(&deg[dst[e]], 1);
}

// single-block exclusive scan of deg[0..NN) -> rowptr; deg becomes pos (= rowptr copy)
__global__ __launch_bounds__(1024) void k_scan(int* __restrict__ deg, int* __restrict__ rowptr) {
    __shared__ int part[1024];
    const int t  = threadIdx.x;
    const int CH = (NN + 1023) / 1024;
    const int b  = t * CH;
    const int e  = min(b + CH, NN);
    int sum = 0;
    for (int i = b; i < e; i++) sum += deg[i];
    part[t] = sum;
    __syncthreads();
    for (int off = 1; off < 1024; off <<= 1) {
        int v = (t >= off) ? part[t - off] : 0;
        __syncthreads();
        part[t] += v;
        __syncthreads();
    }
    int run = (t == 0) ? 0 : part[t - 1];
    for (int i = b; i < e; i++) {
        int d = deg[i];
        rowptr[i] = run;
        deg[i]    = run;   // pos
        run += d;
    }
    if (t == 0) rowptr[NN] = EE;
}

__global__ __launch_bounds__(256) void k_scatter(const int* __restrict__ src, const int* __restrict__ dst,
                                                 int* __restrict__ pos, int* __restrict__ eidx,
                                                 int* __restrict__ esrc) {
    int e = blockIdx.x * 256 + threadIdx.x;
    if (e < EE) {
        int d = dst[e];
        int p = atomicAdd(&pos[d], 1);
        eidx[p] = e;
        esrc[p] = src[e];
    }
}

// ---------------- per-layer kernels ----------------

// K1: per-node fused transform, weights staged in LDS (round-2 version:
// register-resident weights spill to scratch at any occupancy -- do NOT).
__global__ __launch_bounds__(256) void node_transform(
    const float* __restrict__ hin, const float* __restrict__ pot,
    const float* __restrict__ Wpot, const float* __restrict__ bpot,
    const float* __restrict__ fcW, const float* __restrict__ fcU,
    const float* __restrict__ a, const float* __restrict__ gate,
    float* __restrict__ z, float* __restrict__ zs, float* __restrict__ zd,
    float* __restrict__ base)
{
    __shared__ float sW[64 * 64];
    __shared__ float sU[64 * 64];
    __shared__ float sP[16 * 64];
    __shared__ float sb[64], sg[64], sas[64], sad[64];
    for (int i = threadIdx.x; i < 64 * 64; i += 256) { sW[i] = fcW[i]; sU[i] = fcU[i]; }
    for (int i = threadIdx.x; i < 16 * 64; i += 256) sP[i] = Wpot[i];
    if (threadIdx.x < 64) {
        sb[threadIdx.x]  = bpot[threadIdx.x];
        sg[threadIdx.x]  = gate[threadIdx.x];
        sas[threadIdx.x] = a[threadIdx.x];
        sad[threadIdx.x] = a[64 + threadIdx.x];
    }
    __syncthreads();

    const int lane   = threadIdx.x & 63;
    const int wave   = blockIdx.x * 4 + (threadIdx.x >> 6);
    const int nwaves = gridDim.x * 4;

    for (int n = wave; n < NN; n += nwaves) {
        float h = hin[(size_t)n * 64 + lane];
        float p = (lane < 16) ? pot[(size_t)n * 16 + lane] : 0.f;
        float zj = 0.f, zij = 0.f;
#pragma unroll
        for (int k = 0; k < 64; k++) {
            float hk = __shfl(h, k);
            zj  = fmaf(hk, sW[k * 64 + lane], zj);
            zij = fmaf(hk, sU[k * 64 + lane], zij);
        }
        float vj = sb[lane];
#pragma unroll
        for (int k = 0; k < 16; k++) vj = fmaf(__shfl(p, k), sP[k * 64 + lane], vj);
        vj = tanhf(vj);

        float rs = zj * sas[lane];
        float rd = zj * sad[lane];
#pragma unroll
        for (int off = 32; off; off >>= 1) {
            rs += __shfl_xor(rs, off);
            rd += __shfl_xor(rd, off);
        }
        z[(size_t)n * 64 + lane]    = zj;
        base[(size_t)n * 64 + lane] = sg[lane] * vj * zij;
        if (lane == 0) { zs[n] = rs; zd[n] = rd; }
    }
}

// K2: streaming dot for BOTH layers: score_t[e] = et[e,:] . a_t
__device__ __forceinline__ void dot_stream(const float* __restrict__ et,
                                           const float* __restrict__ at,
                                           float* __restrict__ score_t,
                                           int gid, int stride, int lane)
{
    const int p = gid & 15;
    const float4 at4 = *reinterpret_cast<const float4*>(at + p * 4);
    const float4* et4 = reinterpret_cast<const float4*>(et);
    for (int i = gid; i < EE * 16; i += stride) {
        float4 v = et4[i];
        float r = v.x * at4.x + v.y * at4.y + v.z * at4.z + v.w * at4.w;
        r += __shfl_xor(r, 8);
        r += __shfl_xor(r, 4);
        r += __shfl_xor(r, 2);
        r += __shfl_xor(r, 1);
        if ((lane & 15) == 0) score_t[i >> 4] = r;
    }
}

__global__ __launch_bounds__(256) void edge_dot2(
    const float* __restrict__ et0, const float* __restrict__ et1,
    const float* __restrict__ a0, const float* __restrict__ a1,
    float* __restrict__ sc0, float* __restrict__ sc1)
{
    const int gid    = blockIdx.x * 256 + threadIdx.x;
    const int stride = gridDim.x * 256;   // multiple of 16
    const int lane   = threadIdx.x & 63;
    dot_stream(et0, a0 + 128, sc0, gid, stride, lane);
    dot_stream(et1, a1 + 128, sc1, gid, stride, lane);
}

// K3: fused per-node softmax + aggregate + finalize. Wave per node.
__global__ __launch_bounds__(256) void node_sm_agg(
    const int* __restrict__ rowptr, const int* __restrict__ eidx, const int* __restrict__ esrc,
    const float* __restrict__ score_t, const float* __restrict__ zs, const float* __restrict__ zd,
    const float* __restrict__ z, const float* __restrict__ base,
    float* __restrict__ out)
{
    const int lane = threadIdx.x & 63;
    const int n    = blockIdx.x * 4 + (threadIdx.x >> 6);
    if (n >= NN) return;

    const int s0  = rowptr[n], s1 = rowptr[n + 1];
    const int deg = s1 - s0;
    const float zdn = zd[n];

    float acc = 0.f;
    float ds;

    if (deg <= 64) {
        const int j = s0 + lane;
        int   sv = 0;
        float sc = -INFINITY;
        if (j < s1) {
            sv = esrc[j];
            float v = score_t[eidx[j]] + zs[sv] + zdn;
            sc = (v >= 0.f) ? v : 0.01f * v;
        }
        float mx = sc;
#pragma unroll
        for (int off = 32; off; off >>= 1) mx = fmaxf(mx, __shfl_xor(mx, off));
        float ex = (j < s1) ? __expf(sc - mx) : 0.f;
        ds = ex;
#pragma unroll
        for (int off = 32; off; off >>= 1) ds += __shfl_xor(ds, off);
        for (int t = 0; t < deg; t++) {
            int   s = __shfl(sv, t);
            float e = __shfl(ex, t);
            acc = fmaf(e, z[(size_t)s * 64 + lane], acc);
        }
    } else {
        // generic fallback (deg > 64): two passes, recompute scores.
        float mx = -INFINITY;
        for (int j = s0 + lane; j < s1; j += 64) {
            float v = score_t[eidx[j]] + zs[esrc[j]] + zdn;
            v = (v >= 0.f) ? v : 0.01f * v;
            mx = fmaxf(mx, v);
        }
#pragma unroll
        for (int off = 32; off; off >>= 1) mx = fmaxf(mx, __shfl_xor(mx, off));
        ds = 0.f;
        for (int c0 = s0; c0 < s1; c0 += 64) {
            const int j = c0 + lane;
            int   sv = 0;
            float ex = 0.f;
            if (j < s1) {
                sv = esrc[j];
                float v = score_t[eidx[j]] + zs[sv] + zdn;
                v = (v >= 0.f) ? v : 0.01f * v;
                ex = __expf(v - mx);
            }
            ds += ex;
            const int cnt = min(64, s1 - c0);
            for (int t = 0; t < cnt; t++) {
                int   s = __shfl(sv, t);
                float e = __shfl(ex, t);
                acc = fmaf(e, z[(size_t)s * 64 + lane], acc);
            }
        }
#pragma unroll
        for (int off = 32; off; off >>= 1) ds += __shfl_xor(ds, off);
    }

    float r = 1.f / ((ds == 0.f) ? 1.f : ds);
    const size_t o = (size_t)n * 64 + lane;
    out[o] = acc * r + base[o];
}

// ---------------- launch ----------------

extern "C" void kernel_launch(void* const* d_in, const int* in_sizes, int n_in,
                              void* d_out, int out_size, void* d_ws, size_t ws_size,
                              hipStream_t stream)
{
    const float* attr  = (const float*)d_in[0];
    const float* pot0  = (const float*)d_in[1];
    const float* pot1  = (const float*)d_in[2];
    const float* et0   = (const float*)d_in[3];
    const float* et1   = (const float*)d_in[4];
    const float* Wpot  = (const float*)d_in[5];
    const float* bpot  = (const float*)d_in[6];
    const float* fcW0  = (const float*)d_in[7];
    const float* fcU0  = (const float*)d_in[8];
    const float* a0    = (const float*)d_in[9];
    const float* gate0 = (const float*)d_in[10];
    const float* fcW1  = (const float*)d_in[11];
    const float* fcU1  = (const float*)d_in[12];
    const float* a1    = (const float*)d_in[13];
    const float* gate1 = (const float*)d_in[14];
    const int*   src   = (const int*)d_in[15];
    const int*   dst   = (const int*)d_in[16];

    float* out = (float*)d_out;

    // workspace layout
    float* ws      = (float*)d_ws;
    float* z       = ws;                    // NN*64
    float* base    = z + NN * 64;           // NN*64
    float* zs      = base + NN * 64;        // NN
    float* zd      = zs + NN;               // NN
    float* sc0     = zd + NN;               // EE
    float* sc1     = sc0 + EE;              // EE
    int*   rowptr  = (int*)(sc1 + EE);      // NN+1
    int*   deg     = rowptr + NN + 1;       // NN (becomes pos)
    int*   eidx    = deg + NN;              // EE
    int*   esrc    = eidx + EE;             // EE

    const int eblk = (EE + 255) / 256;
    const int nblk = (NN + 3) / 4;

    // CSR build (shared by both layers)
    hipMemsetAsync(deg, 0, NN * sizeof(int), stream);
    k_hist<<<eblk, 256, 0, stream>>>(dst, deg);
    k_scan<<<1, 1024, 0, stream>>>(deg, rowptr);
    k_scatter<<<eblk, 256, 0, stream>>>(src, dst, deg, eidx, esrc);

    // streaming edge dots for both layers (independent of everything above)
    edge_dot2<<<2048, 256, 0, stream>>>(et0, et1, a0, a1, sc0, sc1);

    // ---------------- layer 0 ----------------
    node_transform<<<1024, 256, 0, stream>>>(attr, pot0, Wpot, bpot, fcW0, fcU0,
                                             a0, gate0, z, zs, zd, base);
    node_sm_agg<<<nblk, 256, 0, stream>>>(rowptr, eidx, esrc, sc0, zs, zd, z, base, out);

    // ---------------- layer 1 ---------------- (h = out from layer 0)
    node_transform<<<1024, 256, 0, stream>>>(out, pot1, Wpot, bpot, fcW1, fcU1,
                                             a1, gate1, z, zs, zd, base);
    node_sm_agg<<<nblk, 256, 0, stream>>>(rowptr, eidx, esrc, sc1, zs, zd, z, base, out);
}